// Round 1
// baseline (680.557 us; speedup 1.0000x reference)
//
#include <hip/hip_runtime.h>
#include <hip/hip_bf16.h>
#include <math.h>

// Problem constants
#define NC   192          // channels C
#define ND3  3            // dilations
#define HPD  2            // heads per dilation
#define HDIM 32           // head dim
#define CPD  64           // channels per dilation
#define NV   32768        // voxels = 32^3
#define HIDDEN 768
#define SCALE 0.17677669529663687f  // 32^-0.5

// ---------------------------------------------------------------------------
// Transpose in: x[C,H,W,D] -> h[v=(z*32+y)*32+x][C]
__global__ __launch_bounds__(256) void tin_kernel(const float* __restrict__ xin,
                                                  float* __restrict__ h) {
    __shared__ float lds[32 * 193];
    int yx = blockIdx.x;              // y*32 + x
    int y = yx >> 5, x = yx & 31;
    for (int idx = threadIdx.x; idx < 192 * 32; idx += 256) {
        int c = idx >> 5, z = idx & 31;
        lds[z * 193 + c] = xin[(((size_t)c * 32 + y) * 32 + x) * 32 + z];
    }
    __syncthreads();
    for (int idx = threadIdx.x; idx < 32 * 192; idx += 256) {
        int z = idx / 192, c = idx - z * 192;
        h[((size_t)((z * 32 + y) * 32 + x)) * 192 + c] = lds[z * 193 + c];
    }
}

// Transpose out: h[v][C] -> out[C,H,W,D]
__global__ __launch_bounds__(256) void tout_kernel(const float* __restrict__ h,
                                                   float* __restrict__ outp) {
    __shared__ float lds[32 * 193];
    int yx = blockIdx.x;
    int y = yx >> 5, x = yx & 31;
    for (int idx = threadIdx.x; idx < 32 * 192; idx += 256) {
        int z = idx / 192, c = idx - z * 192;
        lds[z * 193 + c] = h[((size_t)((z * 32 + y) * 32 + x)) * 192 + c];
    }
    __syncthreads();
    for (int idx = threadIdx.x; idx < 192 * 32; idx += 256) {
        int c = idx >> 5, z = idx & 31;
        outp[(((size_t)c * 32 + y) * 32 + x) * 32 + z] = lds[z * 193 + c];
    }
}

// qkv_w [576,192] (o-major) -> wT [192,576] (c-major) so GEMM B is [K][N]
__global__ __launch_bounds__(256) void wt_kernel(const float* __restrict__ w,
                                                 float* __restrict__ wT) {
    int i = blockIdx.x * 256 + threadIdx.x;
    if (i < 576 * 192) {
        int o = i / 192, c = i - o * 192;
        wT[c * 576 + o] = w[i];
    }
}

// LayerNorm over C=192 per voxel. One wave (64 lanes) per voxel, 3 ch/lane.
__global__ __launch_bounds__(256) void ln_kernel(const float* __restrict__ in,
                                                 const float* __restrict__ g,
                                                 const float* __restrict__ be,
                                                 float* __restrict__ out) {
    int wave = threadIdx.x >> 6;
    int lane = threadIdx.x & 63;
    int v = blockIdx.x * 4 + wave;
    const float* row = in + (size_t)v * 192;
    float x0 = row[lane], x1 = row[lane + 64], x2 = row[lane + 128];
    float s = x0 + x1 + x2;
    #pragma unroll
    for (int m = 32; m; m >>= 1) s += __shfl_xor(s, m);
    float mu = s * (1.f / 192.f);
    float d0 = x0 - mu, d1 = x1 - mu, d2 = x2 - mu;
    float s2 = d0 * d0 + d1 * d1 + d2 * d2;
    #pragma unroll
    for (int m = 32; m; m >>= 1) s2 += __shfl_xor(s2, m);
    float rstd = rsqrtf(s2 * (1.f / 192.f) + 1e-5f);
    float* orow = out + (size_t)v * 192;
    orow[lane]       = d0 * rstd * g[lane]       + be[lane];
    orow[lane + 64]  = d1 * rstd * g[lane + 64]  + be[lane + 64];
    orow[lane + 128] = d2 * rstd * g[lane + 128] + be[lane + 128];
}

// Generic fp32 GEMM: C[M,N] = epilogue(A[M,K] @ B[K,N]).
// Tile 64x64, BK=32, 256 threads, 4x4 micro-tile.
// Epilogue: +bias (if bias), GELU (template), +res (if res).  ldc == N.
template <bool GELU>
__global__ __launch_bounds__(256) void gemm_kernel(const float* __restrict__ A,
                                                   const float* __restrict__ B,
                                                   float* __restrict__ C,
                                                   const float* __restrict__ bias,
                                                   const float* __restrict__ res,
                                                   int M, int N, int K) {
    __shared__ float As[32][68];
    __shared__ float Bs[32][68];
    const int tid = threadIdx.x;
    const int m0 = blockIdx.x * 64;
    const int n0 = blockIdx.y * 64;
    const int tm = ((tid >> 4) & 15) << 2;   // 0,4,...,60
    const int tn = (tid & 15) << 2;

    float acc[4][4];
    #pragma unroll
    for (int i = 0; i < 4; ++i)
        #pragma unroll
        for (int j = 0; j < 4; ++j) acc[i][j] = 0.f;

    for (int k0 = 0; k0 < K; k0 += 32) {
        #pragma unroll
        for (int it = 0; it < 2; ++it) {
            int f = tid + it * 256;                 // 0..511
            // A tile: 64 rows x 32 k, stored transposed As[k][m]
            int m  = f >> 3;
            int kq = (f & 7) << 2;
            float4 a = *reinterpret_cast<const float4*>(&A[(size_t)(m0 + m) * K + k0 + kq]);
            As[kq + 0][m] = a.x;
            As[kq + 1][m] = a.y;
            As[kq + 2][m] = a.z;
            As[kq + 3][m] = a.w;
            // B tile: 32 k x 64 n
            int kk = f >> 4;
            int nq = (f & 15) << 2;
            float4 b = *reinterpret_cast<const float4*>(&B[(size_t)(k0 + kk) * N + n0 + nq]);
            *reinterpret_cast<float4*>(&Bs[kk][nq]) = b;
        }
        __syncthreads();
        #pragma unroll
        for (int kk = 0; kk < 32; ++kk) {
            float4 av = *reinterpret_cast<const float4*>(&As[kk][tm]);
            float4 bv = *reinterpret_cast<const float4*>(&Bs[kk][tn]);
            const float aa[4] = {av.x, av.y, av.z, av.w};
            const float bb[4] = {bv.x, bv.y, bv.z, bv.w};
            #pragma unroll
            for (int i = 0; i < 4; ++i)
                #pragma unroll
                for (int j = 0; j < 4; ++j) acc[i][j] += aa[i] * bb[j];
        }
        __syncthreads();
    }

    #pragma unroll
    for (int i = 0; i < 4; ++i) {
        int row = m0 + tm + i;
        float4 v;
        float* vp = &v.x;
        #pragma unroll
        for (int j = 0; j < 4; ++j) {
            float val = acc[i][j];
            int col = n0 + tn + j;
            if (bias) val += bias[col];
            if (GELU) val = 0.5f * val * (1.f + erff(val * 0.70710678118654752f));
            if (res) val += res[(size_t)row * N + col];
            vp[j] = val;
        }
        *reinterpret_cast<float4*>(&C[(size_t)row * N + n0 + tn]) = v;
    }
}

// Attention: one wave per (voxel, dilation). lane = n*32+e (2 heads x 32 dim).
// qkv layout: [v][576] with q at +0, k at +192, v at +384; per-dilation slice di*64.
// Out-of-bounds taps: score exactly 0 (zero-padded k), still in softmax denom.
__global__ __launch_bounds__(64) void attn_kernel(const float* __restrict__ qkv,
                                                  float* __restrict__ attn_out) {
    const int v  = blockIdx.x;
    const int di = blockIdx.y;
    const int r  = di + 1;
    const int z = v >> 10, y = (v >> 5) & 31, x = v & 31;
    const int t = threadIdx.x;

    float q = qkv[(size_t)v * 576 + di * 64 + t];

    float s[27];
    #pragma unroll
    for (int kk = 0; kk < 27; ++kk) {
        int dz = kk / 9 - 1, dy = (kk / 3) % 3 - 1, dx = kk % 3 - 1;
        int nz = z + dz * r, ny = y + dy * r, nx = x + dx * r;
        bool ok = ((unsigned)nz < 32u) & ((unsigned)ny < 32u) & ((unsigned)nx < 32u);
        float sc = 0.f;
        if (ok) {  // wave-uniform branch
            int nv = (nz << 10) + (ny << 5) + nx;
            float kv = qkv[(size_t)nv * 576 + 192 + di * 64 + t];
            float p = q * kv;
            p += __shfl_xor(p, 16);
            p += __shfl_xor(p, 8);
            p += __shfl_xor(p, 4);
            p += __shfl_xor(p, 2);
            p += __shfl_xor(p, 1);
            sc = p * SCALE;
        }
        s[kk] = sc;
    }

    float mx = s[0];
    #pragma unroll
    for (int kk = 1; kk < 27; ++kk) mx = fmaxf(mx, s[kk]);

    float denom = 0.f, o = 0.f;
    #pragma unroll
    for (int kk = 0; kk < 27; ++kk) {
        float p = expf(s[kk] - mx);
        denom += p;
        int dz = kk / 9 - 1, dy = (kk / 3) % 3 - 1, dx = kk % 3 - 1;
        int nz = z + dz * r, ny = y + dy * r, nx = x + dx * r;
        bool ok = ((unsigned)nz < 32u) & ((unsigned)ny < 32u) & ((unsigned)nx < 32u);
        if (ok) {
            int nv = (nz << 10) + (ny << 5) + nx;
            o += p * qkv[(size_t)nv * 576 + 384 + di * 64 + t];
        }
    }
    attn_out[(size_t)v * 192 + di * 64 + t] = o / denom;
}

// ---------------------------------------------------------------------------
extern "C" void kernel_launch(void* const* d_in, const int* in_sizes, int n_in,
                              void* d_out, int out_size, void* d_ws, size_t ws_size,
                              hipStream_t stream) {
    const float* x      = (const float*)d_in[0];
    const float* qkv_w  = (const float*)d_in[1];
    const float* proj_w = (const float*)d_in[2];
    const float* proj_b = (const float*)d_in[3];
    const float* g1     = (const float*)d_in[4];
    const float* be1    = (const float*)d_in[5];
    const float* g2     = (const float*)d_in[6];
    const float* be2    = (const float*)d_in[7];
    const float* w1     = (const float*)d_in[8];
    const float* b1     = (const float*)d_in[9];
    const float* w2     = (const float*)d_in[10];
    const float* b2     = (const float*)d_in[11];
    float* out = (float*)d_out;

    float* ws   = (float*)d_ws;
    float* h    = ws;                    // NV*192 = 6291456
    float* ln   = h + (size_t)NV * 192;  // 6291456
    float* qkv  = ln + (size_t)NV * 192; // NV*576 = 18874368
    float* attn = qkv + (size_t)NV * 576;// 6291456
    float* t    = qkv;                   // NV*768 (overlaps dead qkv+attn)
    float* wT   = attn + (size_t)NV * 192; // 110592

    // 1) layout: x -> h[v][c]
    tin_kernel<<<1024, 256, 0, stream>>>(x, h);
    // 2) transpose qkv weight to [K][N]
    wt_kernel<<<(576 * 192 + 255) / 256, 256, 0, stream>>>(qkv_w, wT);
    // 3) LN1
    ln_kernel<<<NV / 4, 256, 0, stream>>>(h, g1, be1, ln);
    // 4) QKV projection: [NV,192] @ [192,576]
    gemm_kernel<false><<<dim3(NV / 64, 576 / 64), 256, 0, stream>>>(
        ln, wT, qkv, nullptr, nullptr, NV, 576, 192);
    // 5) dilated local attention
    attn_kernel<<<dim3(NV, 3), 64, 0, stream>>>(qkv, attn);
    // 6) proj + bias + residual (in-place into h)
    gemm_kernel<false><<<dim3(NV / 64, 192 / 64), 256, 0, stream>>>(
        attn, proj_w, h, proj_b, h, NV, 192, 192);
    // 7) LN2
    ln_kernel<<<NV / 4, 256, 0, stream>>>(h, g2, be2, ln);
    // 8) MLP fc1 + bias + GELU: [NV,192] @ [192,768]
    gemm_kernel<true><<<dim3(NV / 64, HIDDEN / 64), 256, 0, stream>>>(
        ln, w1, t, b1, nullptr, NV, HIDDEN, 192);
    // 9) MLP fc2 + bias + residual: [NV,768] @ [768,192]
    gemm_kernel<false><<<dim3(NV / 64, 192 / 64), 256, 0, stream>>>(
        t, w2, h, b2, h, NV, 192, HIDDEN);
    // 10) layout back: h -> out[C,H,W,D]
    tout_kernel<<<1024, 256, 0, stream>>>(h, out);
}

// Round 2
// 348.860 us; speedup vs baseline: 1.9508x; 1.9508x over previous
//
#include <hip/hip_runtime.h>
#include <hip/hip_bf16.h>
#include <math.h>

#define NV     32768
#define HIDDEN 768
#define SCALE  0.17677669529663687f

typedef __attribute__((ext_vector_type(8))) short short8;
typedef __attribute__((ext_vector_type(4))) float floatx4;

__device__ __forceinline__ void gload16(const void* g, void* l) {
    __builtin_amdgcn_global_load_lds(
        (const __attribute__((address_space(1))) unsigned int*)g,
        (__attribute__((address_space(3))) unsigned int*)l, 16, 0, 0);
}

// ---------------------------------------------------------------------------
// Transpose in: x[C,H,W,D] -> h[v=(z*32+y)*32+x][C]  (fp32)
__global__ __launch_bounds__(256) void tin_kernel(const float* __restrict__ xin,
                                                  float* __restrict__ h) {
    __shared__ float lds[32 * 193];
    int yx = blockIdx.x;
    int y = yx >> 5, x = yx & 31;
    for (int idx = threadIdx.x; idx < 192 * 32; idx += 256) {
        int c = idx >> 5, z = idx & 31;
        lds[z * 193 + c] = xin[(((size_t)c * 32 + y) * 32 + x) * 32 + z];
    }
    __syncthreads();
    for (int idx = threadIdx.x; idx < 32 * 192; idx += 256) {
        int z = idx / 192, c = idx - z * 192;
        h[((size_t)((z * 32 + y) * 32 + x)) * 192 + c] = lds[z * 193 + c];
    }
}

// Transpose out: h[v][C] -> out[C,H,W,D]
__global__ __launch_bounds__(256) void tout_kernel(const float* __restrict__ h,
                                                   float* __restrict__ outp) {
    __shared__ float lds[32 * 193];
    int yx = blockIdx.x;
    int y = yx >> 5, x = yx & 31;
    for (int idx = threadIdx.x; idx < 32 * 192; idx += 256) {
        int z = idx / 192, c = idx - z * 192;
        lds[z * 193 + c] = h[((size_t)((z * 32 + y) * 32 + x)) * 192 + c];
    }
    __syncthreads();
    for (int idx = threadIdx.x; idx < 192 * 32; idx += 256) {
        int c = idx >> 5, z = idx & 31;
        outp[(((size_t)c * 32 + y) * 32 + x) * 32 + z] = lds[z * 193 + c];
    }
}

// Weight prep: f32 w[R][Cc] -> bf16, optionally transposed to [Cc][R]
__global__ __launch_bounds__(256) void wprep_kernel(const float* __restrict__ w,
                                                    __hip_bfloat16* __restrict__ o,
                                                    int R, int Cc, int tr) {
    int i = blockIdx.x * 256 + threadIdx.x;
    if (i >= R * Cc) return;
    int r = i / Cc, c = i - r * Cc;
    o[tr ? (size_t)c * R + r : (size_t)i] = (__hip_bfloat16)w[i];
}

// LayerNorm over C=192 per voxel, fp32 in -> bf16 out. One wave per voxel.
__global__ __launch_bounds__(256) void ln_kernel(const float* __restrict__ in,
                                                 const float* __restrict__ g,
                                                 const float* __restrict__ be,
                                                 __hip_bfloat16* __restrict__ out) {
    int wave = threadIdx.x >> 6;
    int lane = threadIdx.x & 63;
    int v = blockIdx.x * 4 + wave;
    const float* row = in + (size_t)v * 192;
    float x0 = row[lane], x1 = row[lane + 64], x2 = row[lane + 128];
    float s = x0 + x1 + x2;
    #pragma unroll
    for (int m = 32; m; m >>= 1) s += __shfl_xor(s, m);
    float mu = s * (1.f / 192.f);
    float d0 = x0 - mu, d1 = x1 - mu, d2 = x2 - mu;
    float s2 = d0 * d0 + d1 * d1 + d2 * d2;
    #pragma unroll
    for (int m = 32; m; m >>= 1) s2 += __shfl_xor(s2, m);
    float rstd = rsqrtf(s2 * (1.f / 192.f) + 1e-5f);
    __hip_bfloat16* orow = out + (size_t)v * 192;
    orow[lane]       = (__hip_bfloat16)(d0 * rstd * g[lane]       + be[lane]);
    orow[lane + 64]  = (__hip_bfloat16)(d1 * rstd * g[lane + 64]  + be[lane + 64]);
    orow[lane + 128] = (__hip_bfloat16)(d2 * rstd * g[lane + 128] + be[lane + 128]);
}

// ---------------------------------------------------------------------------
// bf16 MFMA GEMM: C = epi(A[M,K] @ Bw[N,K]^T). 128x64 tile, BK=64, 4 waves.
// MODE 0: plain -> bf16 out. MODE 1: +bias +res(f32) -> f32 out.
// MODE 2: +bias, GELU -> bf16 out.
template <int MODE>
__global__ __launch_bounds__(256, 2) void mgemm_kernel(
        const __hip_bfloat16* __restrict__ A,
        const __hip_bfloat16* __restrict__ Bw,
        void* __restrict__ Cp,
        const float* __restrict__ bias,
        const float* __restrict__ res,
        int M, int N, int K) {
    __shared__ short Asm[128 * 64];
    __shared__ short Bsm[64 * 64];
    const int tid = threadIdx.x;
    const int lane = tid & 63;
    const int wave = tid >> 6;
    const int wm = wave >> 1, wn = wave & 1;
    const int m0 = blockIdx.x * 128;
    const int n0 = blockIdx.y * 64;

    // staging: LDS dest is linear (base + lane*16); pre-swizzle the global col
    const int srow = lane >> 3;                              // row within 8-row seg
    const int scol = ((lane & 7) ^ ((lane >> 3) & 7)) * 16;  // swizzled src col (bytes)

    floatx4 acc[4][2] = {};

    for (int k0 = 0; k0 < K; k0 += 64) {
        #pragma unroll
        for (int s = 0; s < 4; ++s) {                        // A: 16 segs, 4/wave
            int seg = wave * 4 + s;
            const char* g = (const char*)(A + (size_t)(m0 + seg * 8 + srow) * K + k0) + scol;
            gload16(g, (char*)Asm + seg * 1024);
        }
        #pragma unroll
        for (int s = 0; s < 2; ++s) {                        // B: 8 segs, 2/wave
            int seg = wave * 2 + s;
            const char* g = (const char*)(Bw + (size_t)(n0 + seg * 8 + srow) * K + k0) + scol;
            gload16(g, (char*)Bsm + seg * 1024);
        }
        __syncthreads();
        #pragma unroll
        for (int ks = 0; ks < 2; ++ks) {
            short8 af[4], bfr[2];
            const int cb = ks * 64 + (lane >> 4) * 16;
            #pragma unroll
            for (int i = 0; i < 4; ++i) {
                int row = wm * 64 + i * 16 + (lane & 15);
                af[i] = *reinterpret_cast<const short8*>(
                    (const char*)Asm + row * 128 + (cb ^ ((row & 7) << 4)));
            }
            #pragma unroll
            for (int j = 0; j < 2; ++j) {
                int row = wn * 32 + j * 16 + (lane & 15);
                bfr[j] = *reinterpret_cast<const short8*>(
                    (const char*)Bsm + row * 128 + (cb ^ ((row & 7) << 4)));
            }
            #pragma unroll
            for (int i = 0; i < 4; ++i)
                #pragma unroll
                for (int j = 0; j < 2; ++j)
                    acc[i][j] = __builtin_amdgcn_mfma_f32_16x16x32_bf16(
                        af[i], bfr[j], acc[i][j], 0, 0, 0);
        }
        __syncthreads();
    }

    const int r4 = (lane >> 4) * 4;
    const int cc = lane & 15;
    #pragma unroll
    for (int i = 0; i < 4; ++i) {
        #pragma unroll
        for (int j = 0; j < 2; ++j) {
            int colg = n0 + wn * 32 + j * 16 + cc;
            float bv = (MODE != 0) ? bias[colg] : 0.f;
            #pragma unroll
            for (int rg = 0; rg < 4; ++rg) {
                int rowg = m0 + wm * 64 + i * 16 + r4 + rg;
                float v = acc[i][j][rg];
                if (MODE != 0) v += bv;
                if (MODE == 2) v = 0.5f * v * (1.f + erff(v * 0.70710678118654752f));
                if (MODE == 1) {
                    v += res[(size_t)rowg * N + colg];
                    ((float*)Cp)[(size_t)rowg * N + colg] = v;
                } else {
                    ((__hip_bfloat16*)Cp)[(size_t)rowg * N + colg] = (__hip_bfloat16)v;
                }
            }
        }
    }
}

// ---------------------------------------------------------------------------
// Attention: one wave per (voxel, dilation). lane = head*32+e. bf16 in/out.
__global__ __launch_bounds__(64) void attn_kernel(const __hip_bfloat16* __restrict__ qkv,
                                                  __hip_bfloat16* __restrict__ attn_out) {
    const int v  = blockIdx.x;
    const int di = blockIdx.y;
    const int r  = di + 1;
    const int z = v >> 10, y = (v >> 5) & 31, x = v & 31;
    const int t = threadIdx.x;

    float q = __bfloat162float(qkv[(size_t)v * 576 + di * 64 + t]);

    float s[27];
    #pragma unroll
    for (int kk = 0; kk < 27; ++kk) {
        int dz = kk / 9 - 1, dy = (kk / 3) % 3 - 1, dx = kk % 3 - 1;
        int nz = z + dz * r, ny = y + dy * r, nx = x + dx * r;
        bool ok = ((unsigned)nz < 32u) & ((unsigned)ny < 32u) & ((unsigned)nx < 32u);
        float sc = 0.f;
        if (ok) {
            int nv = (nz << 10) + (ny << 5) + nx;
            float kv = __bfloat162float(qkv[(size_t)nv * 576 + 192 + di * 64 + t]);
            float p = q * kv;
            p += __shfl_xor(p, 16);
            p += __shfl_xor(p, 8);
            p += __shfl_xor(p, 4);
            p += __shfl_xor(p, 2);
            p += __shfl_xor(p, 1);
            sc = p * SCALE;
        }
        s[kk] = sc;
    }

    float mx = s[0];
    #pragma unroll
    for (int kk = 1; kk < 27; ++kk) mx = fmaxf(mx, s[kk]);

    float denom = 0.f, o = 0.f;
    #pragma unroll
    for (int kk = 0; kk < 27; ++kk) {
        float p = expf(s[kk] - mx);
        denom += p;
        int dz = kk / 9 - 1, dy = (kk / 3) % 3 - 1, dx = kk % 3 - 1;
        int nz = z + dz * r, ny = y + dy * r, nx = x + dx * r;
        bool ok = ((unsigned)nz < 32u) & ((unsigned)ny < 32u) & ((unsigned)nx < 32u);
        if (ok) {
            int nv = (nz << 10) + (ny << 5) + nx;
            o += p * __bfloat162float(qkv[(size_t)nv * 576 + 384 + di * 64 + t]);
        }
    }
    attn_out[(size_t)v * 192 + di * 64 + t] = (__hip_bfloat16)(o / denom);
}

// ---------------------------------------------------------------------------
extern "C" void kernel_launch(void* const* d_in, const int* in_sizes, int n_in,
                              void* d_out, int out_size, void* d_ws, size_t ws_size,
                              hipStream_t stream) {
    const float* x      = (const float*)d_in[0];
    const float* qkv_w  = (const float*)d_in[1];
    const float* proj_w = (const float*)d_in[2];
    const float* proj_b = (const float*)d_in[3];
    const float* g1     = (const float*)d_in[4];
    const float* be1    = (const float*)d_in[5];
    const float* g2     = (const float*)d_in[6];
    const float* be2    = (const float*)d_in[7];
    const float* w1     = (const float*)d_in[8];
    const float* b1     = (const float*)d_in[9];
    const float* w2     = (const float*)d_in[10];
    const float* b2     = (const float*)d_in[11];
    float* out = (float*)d_out;

    char* p = (char*)d_ws;
    float* h = (float*)p;                 p += (size_t)NV * 192 * 4;
    __hip_bfloat16* lnb   = (__hip_bfloat16*)p;  p += (size_t)NV * 192 * 2;
    __hip_bfloat16* qkvb  = (__hip_bfloat16*)p;  p += (size_t)NV * 576 * 2;
    __hip_bfloat16* attnb = (__hip_bfloat16*)p;  p += (size_t)NV * 192 * 2;
    __hip_bfloat16* tb    = qkvb;  // [NV][768] overlaps dead qkvb+attnb exactly
    __hip_bfloat16* wqkv  = (__hip_bfloat16*)p;  p += (size_t)576 * 192 * 2;
    __hip_bfloat16* wproj = (__hip_bfloat16*)p;  p += (size_t)192 * 192 * 2;
    __hip_bfloat16* w1t   = (__hip_bfloat16*)p;  p += (size_t)768 * 192 * 2;
    __hip_bfloat16* w2t   = (__hip_bfloat16*)p;  p += (size_t)192 * 768 * 2;

    // layout + weight prep
    tin_kernel<<<1024, 256, 0, stream>>>(x, h);
    wprep_kernel<<<(576 * 192 + 255) / 256, 256, 0, stream>>>(qkv_w, wqkv, 576, 192, 0);
    wprep_kernel<<<(192 * 192 + 255) / 256, 256, 0, stream>>>(proj_w, wproj, 192, 192, 1);
    wprep_kernel<<<(192 * 768 + 255) / 256, 256, 0, stream>>>(w1, w1t, 192, 768, 1);
    wprep_kernel<<<(768 * 192 + 255) / 256, 256, 0, stream>>>(w2, w2t, 768, 192, 1);

    // LN1 -> QKV -> attn -> proj(+res)
    ln_kernel<<<NV / 4, 256, 0, stream>>>(h, g1, be1, lnb);
    mgemm_kernel<0><<<dim3(NV / 128, 576 / 64), 256, 0, stream>>>(
        lnb, wqkv, qkvb, nullptr, nullptr, NV, 576, 192);
    attn_kernel<<<dim3(NV, 3), 64, 0, stream>>>(qkvb, attnb);
    mgemm_kernel<1><<<dim3(NV / 128, 192 / 64), 256, 0, stream>>>(
        attnb, wproj, h, proj_b, h, NV, 192, 192);

    // LN2 -> MLP
    ln_kernel<<<NV / 4, 256, 0, stream>>>(h, g2, be2, lnb);
    mgemm_kernel<2><<<dim3(NV / 128, HIDDEN / 64), 256, 0, stream>>>(
        lnb, w1t, tb, b1, nullptr, NV, HIDDEN, 192);
    mgemm_kernel<1><<<dim3(NV / 128, 192 / 64), 256, 0, stream>>>(
        tb, w2t, h, b2, h, NV, 192, HIDDEN);

    tout_kernel<<<1024, 256, 0, stream>>>(h, out);
}

// Round 3
// 202.490 us; speedup vs baseline: 3.3609x; 1.7228x over previous
//
#include <hip/hip_runtime.h>
#include <hip/hip_bf16.h>
#include <math.h>

#define NV     32768
#define HIDDEN 768
#define SCALE  0.17677669529663687f

typedef __attribute__((ext_vector_type(8))) short short8;
typedef __attribute__((ext_vector_type(4))) float floatx4;

__device__ __forceinline__ void gload16(const void* g, void* l) {
    __builtin_amdgcn_global_load_lds(
        (const __attribute__((address_space(1))) unsigned int*)g,
        (__attribute__((address_space(3))) unsigned int*)l, 16, 0, 0);
}

__device__ __forceinline__ float bf2f(short s) {
    unsigned u = ((unsigned)(unsigned short)s) << 16;
    return __builtin_bit_cast(float, u);
}
__device__ __forceinline__ short f2bfs(float f) {
    __hip_bfloat16 b = __float2bfloat16(f);
    return *reinterpret_cast<short*>(&b);
}

// ---------------------------------------------------------------------------
// Transpose in: x[C,H,W,D] -> h[v=(z*32+y)*32+x][C]  (fp32)
__global__ __launch_bounds__(256) void tin_kernel(const float* __restrict__ xin,
                                                  float* __restrict__ h) {
    __shared__ float lds[32 * 193];
    int yx = blockIdx.x;
    int y = yx >> 5, x = yx & 31;
    for (int idx = threadIdx.x; idx < 192 * 32; idx += 256) {
        int c = idx >> 5, z = idx & 31;
        lds[z * 193 + c] = xin[(((size_t)c * 32 + y) * 32 + x) * 32 + z];
    }
    __syncthreads();
    for (int idx = threadIdx.x; idx < 32 * 192; idx += 256) {
        int z = idx / 192, c = idx - z * 192;
        h[((size_t)((z * 32 + y) * 32 + x)) * 192 + c] = lds[z * 193 + c];
    }
}

// Transpose out: h[v][C] -> out[C,H,W,D]
__global__ __launch_bounds__(256) void tout_kernel(const float* __restrict__ h,
                                                   float* __restrict__ outp) {
    __shared__ float lds[32 * 193];
    int yx = blockIdx.x;
    int y = yx >> 5, x = yx & 31;
    for (int idx = threadIdx.x; idx < 32 * 192; idx += 256) {
        int z = idx / 192, c = idx - z * 192;
        lds[z * 193 + c] = h[((size_t)((z * 32 + y) * 32 + x)) * 192 + c];
    }
    __syncthreads();
    for (int idx = threadIdx.x; idx < 192 * 32; idx += 256) {
        int c = idx >> 5, z = idx & 31;
        outp[(((size_t)c * 32 + y) * 32 + x) * 32 + z] = lds[z * 193 + c];
    }
}

// Weight prep: f32 w[R][Cc] -> bf16, optionally transposed to [Cc][R]
__global__ __launch_bounds__(256) void wprep_kernel(const float* __restrict__ w,
                                                    __hip_bfloat16* __restrict__ o,
                                                    int R, int Cc, int tr) {
    int i = blockIdx.x * 256 + threadIdx.x;
    if (i >= R * Cc) return;
    int r = i / Cc, c = i - r * Cc;
    o[tr ? (size_t)c * R + r : (size_t)i] = (__hip_bfloat16)w[i];
}

// LayerNorm over C=192 per voxel, fp32 in -> bf16 out. One wave per voxel.
__global__ __launch_bounds__(256) void ln_kernel(const float* __restrict__ in,
                                                 const float* __restrict__ g,
                                                 const float* __restrict__ be,
                                                 __hip_bfloat16* __restrict__ out) {
    int wave = threadIdx.x >> 6;
    int lane = threadIdx.x & 63;
    int v = blockIdx.x * 4 + wave;
    const float* row = in + (size_t)v * 192;
    float x0 = row[lane], x1 = row[lane + 64], x2 = row[lane + 128];
    float s = x0 + x1 + x2;
    #pragma unroll
    for (int m = 32; m; m >>= 1) s += __shfl_xor(s, m);
    float mu = s * (1.f / 192.f);
    float d0 = x0 - mu, d1 = x1 - mu, d2 = x2 - mu;
    float s2 = d0 * d0 + d1 * d1 + d2 * d2;
    #pragma unroll
    for (int m = 32; m; m >>= 1) s2 += __shfl_xor(s2, m);
    float rstd = rsqrtf(s2 * (1.f / 192.f) + 1e-5f);
    __hip_bfloat16* orow = out + (size_t)v * 192;
    orow[lane]       = (__hip_bfloat16)(d0 * rstd * g[lane]       + be[lane]);
    orow[lane + 64]  = (__hip_bfloat16)(d1 * rstd * g[lane + 64]  + be[lane + 64]);
    orow[lane + 128] = (__hip_bfloat16)(d2 * rstd * g[lane + 128] + be[lane + 128]);
}

// ---------------------------------------------------------------------------
// bf16 MFMA GEMM: C = epi(A[M,K] @ Bw[N,K]^T). 128x64 tile, BK=64, 4 waves.
// MODE 1: +bias +res(f32) -> f32 out. MODE 2: +bias, GELU -> bf16 out.
// MODE 3: scatter into attention layout [part][di][h][v][32] bf16.
template <int MODE>
__global__ __launch_bounds__(256, 2) void mgemm_kernel(
        const __hip_bfloat16* __restrict__ A,
        const __hip_bfloat16* __restrict__ Bw,
        void* __restrict__ Cp,
        const float* __restrict__ bias,
        const float* __restrict__ res,
        int M, int N, int K) {
    __shared__ short Asm[128 * 64];
    __shared__ short Bsm[64 * 64];
    const int tid = threadIdx.x;
    const int lane = tid & 63;
    const int wave = tid >> 6;
    const int wm = wave >> 1, wn = wave & 1;
    const int m0 = blockIdx.x * 128;
    const int n0 = blockIdx.y * 64;

    const int srow = lane >> 3;
    const int scol = ((lane & 7) ^ ((lane >> 3) & 7)) * 16;

    floatx4 acc[4][2] = {};

    for (int k0 = 0; k0 < K; k0 += 64) {
        #pragma unroll
        for (int s = 0; s < 4; ++s) {
            int seg = wave * 4 + s;
            const char* g = (const char*)(A + (size_t)(m0 + seg * 8 + srow) * K + k0) + scol;
            gload16(g, (char*)Asm + seg * 1024);
        }
        #pragma unroll
        for (int s = 0; s < 2; ++s) {
            int seg = wave * 2 + s;
            const char* g = (const char*)(Bw + (size_t)(n0 + seg * 8 + srow) * K + k0) + scol;
            gload16(g, (char*)Bsm + seg * 1024);
        }
        __syncthreads();
        #pragma unroll
        for (int ks = 0; ks < 2; ++ks) {
            short8 af[4], bfr[2];
            const int cb = ks * 64 + (lane >> 4) * 16;
            #pragma unroll
            for (int i = 0; i < 4; ++i) {
                int row = wm * 64 + i * 16 + (lane & 15);
                af[i] = *reinterpret_cast<const short8*>(
                    (const char*)Asm + row * 128 + (cb ^ ((row & 7) << 4)));
            }
            #pragma unroll
            for (int j = 0; j < 2; ++j) {
                int row = wn * 32 + j * 16 + (lane & 15);
                bfr[j] = *reinterpret_cast<const short8*>(
                    (const char*)Bsm + row * 128 + (cb ^ ((row & 7) << 4)));
            }
            #pragma unroll
            for (int i = 0; i < 4; ++i)
                #pragma unroll
                for (int j = 0; j < 2; ++j)
                    acc[i][j] = __builtin_amdgcn_mfma_f32_16x16x32_bf16(
                        af[i], bfr[j], acc[i][j], 0, 0, 0);
        }
        __syncthreads();
    }

    const int r4 = (lane >> 4) * 4;
    const int cc = lane & 15;
    #pragma unroll
    for (int i = 0; i < 4; ++i) {
        #pragma unroll
        for (int j = 0; j < 2; ++j) {
            int colg = n0 + wn * 32 + j * 16 + cc;
            float bv = (MODE == 1 || MODE == 2) ? bias[colg] : 0.f;
            #pragma unroll
            for (int rg = 0; rg < 4; ++rg) {
                int rowg = m0 + wm * 64 + i * 16 + r4 + rg;
                float v = acc[i][j][rg];
                if (MODE == 1 || MODE == 2) v += bv;
                if (MODE == 2) v = 0.5f * v * (1.f + erff(v * 0.70710678118654752f));
                if (MODE == 1) {
                    v += res[(size_t)rowg * N + colg];
                    ((float*)Cp)[(size_t)rowg * N + colg] = v;
                } else if (MODE == 2) {
                    ((__hip_bfloat16*)Cp)[(size_t)rowg * N + colg] = (__hip_bfloat16)v;
                } else {  // MODE 3: part/di/h scatter
                    int part = colg / 192;
                    int rem  = colg - part * 192;
                    int di   = rem >> 6, hc = rem & 63;
                    size_t addr = (size_t)part * (6 * (size_t)NV * 32)
                                + (size_t)((di << 1) + (hc >> 5)) * ((size_t)NV * 32)
                                + (size_t)rowg * 32 + (hc & 31);
                    ((__hip_bfloat16*)Cp)[addr] = (__hip_bfloat16)v;
                }
            }
        }
    }
}

// ---------------------------------------------------------------------------
// Attention: lane-per-voxel. Wave = 2 y-rows x 32 x for one (di, head).
// Layouts qa/ka/va: [(di*2+h)][v][32ch] bf16 (64B per voxel).
__global__ __launch_bounds__(256) void attn_kernel(
        const __hip_bfloat16* __restrict__ qa,
        const __hip_bfloat16* __restrict__ ka,
        const __hip_bfloat16* __restrict__ va,
        __hip_bfloat16* __restrict__ attn_out) {
    const int dh = blockIdx.y;          // di*2+h
    const int di = dh >> 1;
    const int r  = di + 1;
    const int zb = blockIdx.x;          // z*4 + ygroup
    const int z  = zb >> 2;
    const int wave = threadIdx.x >> 6, lane = threadIdx.x & 63;
    const int y = ((zb & 3) << 3) + (wave << 1) + (lane >> 5);
    const int x = lane & 31;
    const int v = (z << 10) + (y << 5) + x;
    const size_t base = (size_t)dh * NV * 32;

    // q into registers (f32)
    float qf[32];
    {
        const short8* qp = reinterpret_cast<const short8*>(qa + base + (size_t)v * 32);
        #pragma unroll
        for (int j = 0; j < 4; ++j) {
            short8 qv = qp[j];
            #pragma unroll
            for (int u = 0; u < 8; ++u) qf[j * 8 + u] = bf2f(qv[u]);
        }
    }

    float s[27];
    int nvs[27];
    unsigned vmask = 0;
    #pragma unroll
    for (int kk = 0; kk < 27; ++kk) {
        const int dz = kk / 9 - 1, dy = (kk / 3) % 3 - 1, dx = kk % 3 - 1;
        int nz = z + dz * r, ny = y + dy * r, nx = x + dx * r;
        bool ok = ((unsigned)nz < 32u) & ((unsigned)ny < 32u) & ((unsigned)nx < 32u);
        int nv = ok ? (nz << 10) + (ny << 5) + nx : v;
        nvs[kk] = nv;
        vmask |= (ok ? 1u : 0u) << kk;
        const short8* kp = reinterpret_cast<const short8*>(ka + base + (size_t)nv * 32);
        float d0 = 0.f, d1 = 0.f;
        #pragma unroll
        for (int j = 0; j < 4; ++j) {
            short8 kv = kp[j];
            #pragma unroll
            for (int u = 0; u < 8; u += 2) {
                d0 += qf[j * 8 + u]     * bf2f(kv[u]);
                d1 += qf[j * 8 + u + 1] * bf2f(kv[u + 1]);
            }
        }
        s[kk] = ok ? (d0 + d1) * SCALE : 0.f;
    }

    float mx = s[0];
    #pragma unroll
    for (int kk = 1; kk < 27; ++kk) mx = fmaxf(mx, s[kk]);

    float denom = 0.f;
    #pragma unroll
    for (int kk = 0; kk < 27; ++kk) {
        float p = __expf(s[kk] - mx);
        denom += p;
        s[kk] = p;
    }
    float inv = 1.f / denom;

    float o[32];
    #pragma unroll
    for (int c = 0; c < 32; ++c) o[c] = 0.f;
    #pragma unroll
    for (int kk = 0; kk < 27; ++kk) {
        float w = ((vmask >> kk) & 1u) ? s[kk] : 0.f;
        const short8* vp = reinterpret_cast<const short8*>(va + base + (size_t)nvs[kk] * 32);
        #pragma unroll
        for (int j = 0; j < 4; ++j) {
            short8 vv = vp[j];
            #pragma unroll
            for (int u = 0; u < 8; ++u) o[j * 8 + u] += w * bf2f(vv[u]);
        }
    }

    __hip_bfloat16* op = attn_out + (size_t)v * 192 + di * 64 + (dh & 1) * 32;
    #pragma unroll
    for (int j = 0; j < 4; ++j) {
        short8 st;
        #pragma unroll
        for (int u = 0; u < 8; ++u) st[u] = f2bfs(o[j * 8 + u] * inv);
        *reinterpret_cast<short8*>(op + j * 8) = st;
    }
}

// ---------------------------------------------------------------------------
extern "C" void kernel_launch(void* const* d_in, const int* in_sizes, int n_in,
                              void* d_out, int out_size, void* d_ws, size_t ws_size,
                              hipStream_t stream) {
    const float* x      = (const float*)d_in[0];
    const float* qkv_w  = (const float*)d_in[1];
    const float* proj_w = (const float*)d_in[2];
    const float* proj_b = (const float*)d_in[3];
    const float* g1     = (const float*)d_in[4];
    const float* be1    = (const float*)d_in[5];
    const float* g2     = (const float*)d_in[6];
    const float* be2    = (const float*)d_in[7];
    const float* w1     = (const float*)d_in[8];
    const float* b1     = (const float*)d_in[9];
    const float* w2     = (const float*)d_in[10];
    const float* b2     = (const float*)d_in[11];
    float* out = (float*)d_out;

    char* p = (char*)d_ws;
    float* h = (float*)p;                        p += (size_t)NV * 192 * 4;
    __hip_bfloat16* lnb   = (__hip_bfloat16*)p;  p += (size_t)NV * 192 * 2;
    __hip_bfloat16* qkvb  = (__hip_bfloat16*)p;  p += (size_t)NV * 576 * 2;
    __hip_bfloat16* attnb = (__hip_bfloat16*)p;  p += (size_t)NV * 192 * 2;
    __hip_bfloat16* tb    = qkvb;  // [NV][768] overlaps dead qkvb+attnb exactly
    __hip_bfloat16* wqkv  = (__hip_bfloat16*)p;  p += (size_t)576 * 192 * 2;
    __hip_bfloat16* wproj = (__hip_bfloat16*)p;  p += (size_t)192 * 192 * 2;
    __hip_bfloat16* w1t   = (__hip_bfloat16*)p;  p += (size_t)768 * 192 * 2;
    __hip_bfloat16* w2t   = (__hip_bfloat16*)p;  p += (size_t)192 * 768 * 2;

    __hip_bfloat16* qa = qkvb;
    __hip_bfloat16* ka = qkvb + (size_t)6 * NV * 32;
    __hip_bfloat16* va = qkvb + (size_t)12 * NV * 32;

    // layout + weight prep
    tin_kernel<<<1024, 256, 0, stream>>>(x, h);
    wprep_kernel<<<(576 * 192 + 255) / 256, 256, 0, stream>>>(qkv_w, wqkv, 576, 192, 0);
    wprep_kernel<<<(192 * 192 + 255) / 256, 256, 0, stream>>>(proj_w, wproj, 192, 192, 1);
    wprep_kernel<<<(192 * 768 + 255) / 256, 256, 0, stream>>>(w1, w1t, 192, 768, 1);
    wprep_kernel<<<(768 * 192 + 255) / 256, 256, 0, stream>>>(w2, w2t, 768, 192, 1);

    // LN1 -> QKV (scatter to attn layout) -> attn -> proj(+res)
    ln_kernel<<<NV / 4, 256, 0, stream>>>(h, g1, be1, lnb);
    mgemm_kernel<3><<<dim3(NV / 128, 576 / 64), 256, 0, stream>>>(
        lnb, wqkv, qkvb, nullptr, nullptr, NV, 576, 192);
    attn_kernel<<<dim3(128, 6), 256, 0, stream>>>(qa, ka, va, attnb);
    mgemm_kernel<1><<<dim3(NV / 128, 192 / 64), 256, 0, stream>>>(
        attnb, wproj, h, proj_b, h, NV, 192, 192);

    // LN2 -> MLP
    ln_kernel<<<NV / 4, 256, 0, stream>>>(h, g2, be2, lnb);
    mgemm_kernel<2><<<dim3(NV / 128, HIDDEN / 64), 256, 0, stream>>>(
        lnb, w1t, tb, b1, nullptr, NV, HIDDEN, 192);
    mgemm_kernel<1><<<dim3(NV / 128, 192 / 64), 256, 0, stream>>>(
        tb, w2t, h, b2, h, NV, 192, HIDDEN);

    tout_kernel<<<1024, 256, 0, stream>>>(h, out);
}